// Round 12
// baseline (293.241 us; speedup 1.0000x reference)
//
#include <hip/hip_runtime.h>
#include <math.h>

#define BB   8
#define NVV  10242
#define NFF  20480
#define EPSBN 1e-5f
#define GRAM_BLOCKS 644   // x 2 chunks each = 1288 = 8 batches * 161 vert-chunks

typedef __attribute__((ext_vector_type(8))) short bf16x8_t;
typedef __attribute__((ext_vector_type(4))) float f32x4_t;

__device__ inline float bf2f(ushort u) {
    union { uint i; float f; } v; v.i = ((uint)u) << 16; return v.f;
}
__device__ inline ushort f2bf(float f) {
    union { float f; uint i; } v; v.f = f;
    const uint r = v.i + 0x7fffu + ((v.i >> 16) & 1u);
    return (ushort)(r >> 16);
}
__device__ inline void unpack2(uint w, float& lo, float& hi) {
    union { uint i; float f; } a, b;
    a.i = w << 16; b.i = w & 0xffff0000u;
    lo = a.f; hi = b.f;
}
__device__ inline uint pack2(float lo, float hi) {
    return (uint)f2bf(lo) | ((uint)f2bf(hi) << 16);
}
__device__ inline void fma8(const uint4 hv, const float w, float s[8]) {
    float lo, hi;
    unpack2(hv.x, lo, hi); s[0] = fmaf(w, lo, s[0]); s[1] = fmaf(w, hi, s[1]);
    unpack2(hv.y, lo, hi); s[2] = fmaf(w, lo, s[2]); s[3] = fmaf(w, hi, s[3]);
    unpack2(hv.z, lo, hi); s[4] = fmaf(w, lo, s[4]); s[5] = fmaf(w, hi, s[5]);
    unpack2(hv.w, lo, hi); s[6] = fmaf(w, lo, s[6]); s[7] = fmaf(w, hi, s[7]);
}
__device__ inline void fma8x2(const uint4 hv, const float wa, const float wb,
                              float sa[8], float sb[8]) {
    float lo, hi;
    unpack2(hv.x, lo, hi);
    sa[0] = fmaf(wa, lo, sa[0]); sb[0] = fmaf(wb, lo, sb[0]);
    sa[1] = fmaf(wa, hi, sa[1]); sb[1] = fmaf(wb, hi, sb[1]);
    unpack2(hv.y, lo, hi);
    sa[2] = fmaf(wa, lo, sa[2]); sb[2] = fmaf(wb, lo, sb[2]);
    sa[3] = fmaf(wa, hi, sa[3]); sb[3] = fmaf(wb, hi, sb[3]);
    unpack2(hv.z, lo, hi);
    sa[4] = fmaf(wa, lo, sa[4]); sb[4] = fmaf(wb, lo, sb[4]);
    sa[5] = fmaf(wa, hi, sa[5]); sb[5] = fmaf(wb, hi, sb[5]);
    unpack2(hv.w, lo, hi);
    sa[6] = fmaf(wa, lo, sa[6]); sb[6] = fmaf(wb, lo, sb[6]);
    sa[7] = fmaf(wa, hi, sa[7]); sb[7] = fmaf(wb, hi, sb[7]);
}
__device__ inline uint4 pack8(const float s[8]) {
    uint4 p;
    p.x = pack2(s[0], s[1]); p.y = pack2(s[2], s[3]);
    p.z = pack2(s[4], s[5]); p.w = pack2(s[6], s[7]);
    return p;
}

// ---------------------------------------------------------------------------
// K0: Gram partials via MFMA bf16 hi/lo split + xsum partials + xT bf16 write.
// ---------------------------------------------------------------------------
__global__ __launch_bounds__(256)
void gram_kernel(const float* __restrict__ x, float* __restrict__ gramPart,
                 float* __restrict__ xsumPart, uint* __restrict__ xTu)
{
    __shared__ __align__(16) ushort Ahi[128 * 64];
    __shared__ __align__(16) ushort Alo[128 * 64];
    const int t = threadIdx.x;
    const int l = t & 63, wid = t >> 6;
    const int l15 = l & 15, l4 = l >> 4;
    f32x4_t acc[2][8];
#pragma unroll
    for (int m = 0; m < 2; ++m)
#pragma unroll
        for (int n = 0; n < 8; ++n) acc[m][n] = (f32x4_t){0.f, 0.f, 0.f, 0.f};
    float xs[8] = {0.f, 0.f, 0.f, 0.f, 0.f, 0.f, 0.f, 0.f};

    for (int s = 0; s < 2; ++s) {
        const int cc = blockIdx.x * 2 + s;
        const int b = cc / 161, tb = cc % 161, v0 = tb * 64;
#pragma unroll
        for (int i = 0; i < 8; ++i) {
            const int item = t + (i << 8);
            const int c = item >> 4, vq = item & 15;
            const int gv = v0 + (vq << 2);
            const float* xp = x + ((size_t)b * 128 + c) * NVV + gv;
            float4 xv = make_float4(0.f, 0.f, 0.f, 0.f);
            if (gv + 4 <= NVV) {
                xv = *reinterpret_cast<const float4*>(xp);
            } else {
                if (gv     < NVV) xv.x = xp[0];
                if (gv + 1 < NVV) xv.y = xp[1];
            }
            xs[i] += xv.x + xv.y + xv.z + xv.w;
            const ushort h0 = f2bf(xv.x), h1 = f2bf(xv.y), h2 = f2bf(xv.z), h3 = f2bf(xv.w);
            const ushort e0 = f2bf(xv.x - bf2f(h0)), e1 = f2bf(xv.y - bf2f(h1));
            const ushort e2 = f2bf(xv.z - bf2f(h2)), e3 = f2bf(xv.w - bf2f(h3));
            uint2 hp, lp;
            hp.x = (uint)h0 | ((uint)h1 << 16); hp.y = (uint)h2 | ((uint)h3 << 16);
            lp.x = (uint)e0 | ((uint)e1 << 16); lp.y = (uint)e2 | ((uint)e3 << 16);
            const int byte = (c << 7) + (vq << 3);
            const int swz = byte ^ ((c & 7) << 4);
            *reinterpret_cast<uint2*>((char*)Ahi + swz) = hp;
            *reinterpret_cast<uint2*>((char*)Alo + swz) = lp;
        }
        __syncthreads();
        {
            const int v = t & 63, cq = t >> 6;
            const int gv = v0 + v;
            if (gv < NVV) {
                uint4* rowp = reinterpret_cast<uint4*>(xTu + ((size_t)b * NVV + gv) * 64) + (cq << 2);
#pragma unroll
                for (int k2 = 0; k2 < 4; ++k2) {
                    uint wrd[4];
#pragma unroll
                    for (int w2 = 0; w2 < 4; ++w2) {
                        const int c0 = (cq << 5) + (k2 << 3) + (w2 << 1);
                        const int b0 = ((c0) << 7) + (v << 1);
                        const int b1 = ((c0 + 1) << 7) + (v << 1);
                        const ushort q0 = *reinterpret_cast<const ushort*>((const char*)Ahi + (b0 ^ ((c0 & 7) << 4)));
                        const ushort q1 = *reinterpret_cast<const ushort*>((const char*)Ahi + (b1 ^ (((c0 + 1) & 7) << 4)));
                        wrd[w2] = (uint)q0 | ((uint)q1 << 16);
                    }
                    rowp[k2] = make_uint4(wrd[0], wrd[1], wrd[2], wrd[3]);
                }
            }
        }
#pragma unroll
        for (int kk2 = 0; kk2 < 2; ++kk2) {
            bf16x8_t ah[2], al[2];
#pragma unroll
            for (int m = 0; m < 2; ++m) {
                const int row = wid * 32 + m * 16 + l15;
                const int byte = (row << 7) + (kk2 << 6) + (l4 << 4);
                ah[m] = *reinterpret_cast<const bf16x8_t*>((const char*)Ahi + (byte ^ ((row & 7) << 4)));
                al[m] = *reinterpret_cast<const bf16x8_t*>((const char*)Alo + (byte ^ ((row & 7) << 4)));
            }
#pragma unroll
            for (int n = 0; n < 8; ++n) {
                const int rn = n * 16 + l15;
                const int byte = (rn << 7) + (kk2 << 6) + (l4 << 4);
                const bf16x8_t bh = *reinterpret_cast<const bf16x8_t*>((const char*)Ahi + (byte ^ ((rn & 7) << 4)));
                const bf16x8_t bl = *reinterpret_cast<const bf16x8_t*>((const char*)Alo + (byte ^ ((rn & 7) << 4)));
#pragma unroll
                for (int m = 0; m < 2; ++m) {
                    acc[m][n] = __builtin_amdgcn_mfma_f32_16x16x32_bf16(ah[m], bh, acc[m][n], 0, 0, 0);
                    acc[m][n] = __builtin_amdgcn_mfma_f32_16x16x32_bf16(ah[m], bl, acc[m][n], 0, 0, 0);
                    acc[m][n] = __builtin_amdgcn_mfma_f32_16x16x32_bf16(al[m], bh, acc[m][n], 0, 0, 0);
                }
            }
        }
        __syncthreads();
    }
    float* gp = gramPart + (size_t)blockIdx.x * 16384;
#pragma unroll
    for (int m = 0; m < 2; ++m)
#pragma unroll
        for (int n = 0; n < 8; ++n)
#pragma unroll
            for (int j = 0; j < 4; ++j) {
                const int row = wid * 32 + m * 16 + l4 * 4 + j;
                const int col = n * 16 + l15;
                gp[row * 128 + col] = acc[m][n][j];
            }
#pragma unroll
    for (int i = 0; i < 8; ++i) {
        xs[i] += __shfl_xor(xs[i], 1);
        xs[i] += __shfl_xor(xs[i], 2);
        xs[i] += __shfl_xor(xs[i], 4);
        xs[i] += __shfl_xor(xs[i], 8);
    }
    if ((l & 15) == 0) {
#pragma unroll
        for (int i = 0; i < 8; ++i)
            xsumPart[(size_t)blockIdx.x * 128 + wid * 4 + l4 + i * 16] = xs[i];
    }
}

__global__ void reduce_gram_kernel(const float* __restrict__ gp, const float* __restrict__ xp,
                                   float* __restrict__ Gram, float* __restrict__ xsum)
{
    const int tid = blockIdx.x * 256 + threadIdx.x;
    for (int e = tid; e < 16384; e += 64 * 256) {
        float s = 0.f;
        for (int i = 0; i < GRAM_BLOCKS; ++i) s += gp[(size_t)i * 16384 + e];
        Gram[e] = s;
    }
    if (blockIdx.x == 0 && threadIdx.x < 128) {
        float s = 0.f;
        for (int i = 0; i < GRAM_BLOCKS; ++i) s += xp[(size_t)i * 128 + threadIdx.x];
        xsum[threadIdx.x] = s;
    }
}

// ---------------------------------------------------------------------------
// K1: analytic BN folding for conv1a (128 ch) and conv1b (256 ch)
// ---------------------------------------------------------------------------
__global__ __launch_bounds__(128)
void stats_ab_kernel(const float* __restrict__ Gram, const float* __restrict__ xsum,
                     const float* __restrict__ w1a, const float* __restrict__ g1a,
                     const float* __restrict__ be1a,
                     const float* __restrict__ w1b, const float* __restrict__ g1b,
                     const float* __restrict__ be1b,
                     float* __restrict__ alpha_a, float* __restrict__ beta_a,
                     float* __restrict__ alpha_b, float* __restrict__ beta_b)
{
    const int t = threadIdx.x;
    const int cc = blockIdx.x;
    const float invN = 1.f / (float)(BB * NVV);
    const bool isA = cc < 128;
    const int c = isA ? cc : cc - 128;
    const float* Wrow = isA ? (w1a + (size_t)c * 128) : (w1b + (size_t)c * 128);
    __shared__ float Wr[128];
    __shared__ float red[4];
    Wr[t] = Wrow[t];
    __syncthreads();
    float gi = 0.f;
    const float* Grow = Gram + (size_t)t * 128;
    for (int j = 0; j < 128; ++j) gi = fmaf(Grow[j], Wr[j], gi);
    float pi = Wr[t] * gi * invN;
    float qi = (xsum[t] * invN) * Wr[t];
    for (int off = 32; off > 0; off >>= 1) {
        pi += __shfl_down(pi, off);
        qi += __shfl_down(qi, off);
    }
    const int wid = t >> 6;
    if ((t & 63) == 0) { red[wid] = pi; red[2 + wid] = qi; }
    __syncthreads();
    if (t == 0) {
        const float P = red[0] + red[1], Q = red[2] + red[3];
        const float var = P - Q * Q;
        const float g = isA ? g1a[c] : g1b[c];
        const float be = isA ? be1a[c] : be1b[c];
        const float a = g * rsqrtf(var + EPSBN);
        if (isA) { alpha_a[c] = a; beta_a[c] = be - a * Q; }
        else     { alpha_b[c] = a; beta_b[c] = be - a * Q; }
    }
}

// ---------------------------------------------------------------------------
// Prepack weights (fp32 -> bf16, swizzled LDS image). 5 slabs x 2 kc-chunks.
// ---------------------------------------------------------------------------
__global__ __launch_bounds__(256)
void prepack_weights_kernel(const float* __restrict__ w1a, const float* __restrict__ w1b,
                            const float* __restrict__ w3a, uint* __restrict__ wpk)
{
    const int j = blockIdx.x * 256 + threadIdx.x;       // 0..40959
    const int seg = j >> 12;                             // slab*2 + kcIdx
    const int slab = seg >> 1, kc = (seg & 1) << 6;
    const int u = j & 4095;
    const int o = u >> 5;
    const int inner = (u << 2) & 127;
    const int inner0 = inner ^ ((o & 7) << 4);
    const int kp = inner0 >> 2;
    const float* W;
    if (slab == 0)      W = w1a;
    else if (slab <= 2) W = w1b + (size_t)(slab - 1) * 128 * 128;
    else                W = w3a + (size_t)(slab - 3) * 128 * 128;
    const float2 wv = *reinterpret_cast<const float2*>(&W[(size_t)o * 128 + kc + 2 * kp]);
    wpk[j] = pack2(wv.x, wv.y);
}

// ---------------------------------------------------------------------------
// Prepack coeffs -> swizzled LDS images, 10 chunks x 4096 uints:
// chunks 0-3: mesh (q0=id -> C0, q1=lap -> C1) x c_half
// chunks 4-5: identity B for the gfc injection (per c_half)
// chunks 6-9: face GEMM B = [C2;C3] in 4 K-chunks of 64
// ---------------------------------------------------------------------------
__global__ __launch_bounds__(256)
void prepack_coeffs_kernel(const float* __restrict__ coeffs, uint* __restrict__ cpk)
{
    const int j = blockIdx.x * 256 + threadIdx.x;    // grid 160 -> 40960
    const int chunk = j >> 12, u = j & 4095;
    const int o = u >> 5;
    const int inner = (u << 2) & 127;
    const int inner0 = inner ^ ((o & 7) << 4);
    const int p = inner0 >> 2;                        // k pair (2p, 2p+1)
    float v0f, v1f;
    if (chunk < 4) {
        const int q = chunk >> 1, c0 = (chunk & 1) << 6;
        const int row0 = (c0 + 2 * p) * 4 + q;
        v0f = coeffs[(size_t)row0 * 128 + o];
        v1f = coeffs[(size_t)(row0 + 4) * 128 + o];
    } else if (chunk < 6) {
        const int c0 = (chunk - 4) << 6;
        v0f = (o == c0 + 2 * p) ? 1.f : 0.f;
        v1f = (o == c0 + 2 * p + 1) ? 1.f : 0.f;
    } else {
        const int kc = chunk - 6;
        const int kg0 = kc * 64 + 2 * p;
        const int row0 = (kg0 < 128) ? (kg0 * 4 + 2) : ((kg0 - 128) * 4 + 3);
        const int row1 = (kg0 + 1 < 128) ? ((kg0 + 1) * 4 + 2) : ((kg0 + 1 - 128) * 4 + 3);
        v0f = coeffs[(size_t)row0 * 128 + o];
        v1f = coeffs[(size_t)row1 * 128 + o];
    }
    cpk[j] = pack2(v0f, v1f);
}

// ---------------------------------------------------------------------------
// z-fused MFMA conv, 64-row blocks (stats aliased into Bs).
// ---------------------------------------------------------------------------
template <int MODE>
__global__ __launch_bounds__(256)
void mfma_conv_kernel(const ushort* __restrict__ Asrc, const uint4* __restrict__ wpk,
                      const float* __restrict__ aIn, const float* __restrict__ bIn,
                      const float* __restrict__ aA, const float* __restrict__ bA,
                      const float* __restrict__ aB, const float* __restrict__ bB,
                      ushort* __restrict__ hOut, ushort* __restrict__ x2Out,
                      ushort* __restrict__ x1Out,
                      float* __restrict__ statSum, float* __restrict__ statSsq)
{
    __shared__ __align__(16) ushort As[64 * 128];
    __shared__ __align__(16) ushort Bs[128 * 64];
    float* statS = (float*)Bs;            // aliased: Bs dead when stats used
    float* statQ = (float*)Bs + 512;
    const int t = threadIdx.x;
    const int bid = blockIdx.x;
    const int b = bid & 7, vblk = bid >> 3;
    const int v0 = vblk * 64;
    const int l = t & 63, wid = t >> 6;
    const int l15 = l & 15, l4 = l >> 4;

#pragma unroll
    for (int i = 0; i < 4; ++i) {
        const int item = t + (i << 8);
        const int r = item >> 4, piece = item & 15;
        const int cb = piece * 8;
        const int v = v0 + r;
        uint4 pk = make_uint4(0u, 0u, 0u, 0u);
        if (v < NVV) {
            pk = *reinterpret_cast<const uint4*>(Asrc + ((size_t)b * NVV + v) * 128 + cb);
            if (MODE == 1) {
                float s[8];
                unpack2(pk.x, s[0], s[1]); unpack2(pk.y, s[2], s[3]);
                unpack2(pk.z, s[4], s[5]); unpack2(pk.w, s[6], s[7]);
                const float4 a0 = *reinterpret_cast<const float4*>(&aIn[cb]);
                const float4 a1 = *reinterpret_cast<const float4*>(&aIn[cb + 4]);
                const float4 b0 = *reinterpret_cast<const float4*>(&bIn[cb]);
                const float4 b1 = *reinterpret_cast<const float4*>(&bIn[cb + 4]);
                s[0] = fmaxf(fmaf(a0.x, s[0], b0.x), 0.f);
                s[1] = fmaxf(fmaf(a0.y, s[1], b0.y), 0.f);
                s[2] = fmaxf(fmaf(a0.z, s[2], b0.z), 0.f);
                s[3] = fmaxf(fmaf(a0.w, s[3], b0.w), 0.f);
                s[4] = fmaxf(fmaf(a1.x, s[4], b1.x), 0.f);
                s[5] = fmaxf(fmaf(a1.y, s[5], b1.y), 0.f);
                s[6] = fmaxf(fmaf(a1.z, s[6], b1.z), 0.f);
                s[7] = fmaxf(fmaf(a1.w, s[7], b1.w), 0.f);
                pk = pack8(s);
            }
        }
        const int byte = (r << 8) + (piece << 4);
        *reinterpret_cast<uint4*>((char*)As + (byte ^ ((r & 7) << 4))) = pk;
    }

    const int NZ = (MODE == 0) ? 3 : 2;
    for (int z = 0; z < NZ; ++z) {
        const int slab = (MODE == 0) ? z : (3 + z);
        f32x4_t acc[8];
#pragma unroll
        for (int n = 0; n < 8; ++n) acc[n] = (f32x4_t){0.f, 0.f, 0.f, 0.f};

        for (int kc = 0; kc < 128; kc += 64) {
            const uint4* wseg = wpk + (size_t)(slab * 2 + (kc >> 6)) * 1024;
#pragma unroll
            for (int i = 0; i < 4; ++i)
                reinterpret_cast<uint4*>(Bs)[t + (i << 8)] = wseg[t + (i << 8)];
            __syncthreads();
#pragma unroll
            for (int kk2 = 0; kk2 < 2; ++kk2) {
                const int row = wid * 16 + l15;
                const int abyte = (row << 8) + (kc << 1) + (kk2 << 6) + (l4 << 4);
                const bf16x8_t af = *reinterpret_cast<const bf16x8_t*>(
                    (const char*)As + (abyte ^ ((row & 7) << 4)));
#pragma unroll
                for (int n = 0; n < 8; ++n) {
                    const int o = n * 16 + l15;
                    const int bbyte = (o << 7) + (kk2 << 6) + (l4 << 4);
                    const bf16x8_t bfr = *reinterpret_cast<const bf16x8_t*>(
                        (const char*)Bs + (bbyte ^ ((o & 7) << 4)));
                    acc[n] = __builtin_amdgcn_mfma_f32_16x16x32_bf16(af, bfr, acc[n], 0, 0, 0);
                }
            }
            __syncthreads();
        }

        if (MODE == 0 && z == 0) {
            float aO[8], bO[8];
#pragma unroll
            for (int n = 0; n < 8; ++n) {
                const int c = n * 16 + l15;
                aO[n] = aA[c]; bO[n] = bA[c];
            }
#pragma unroll
            for (int j = 0; j < 4; ++j) {
                const int v = v0 + wid * 16 + l4 * 4 + j;
                if (v < NVV) {
                    ushort* mp = hOut + ((size_t)b * NVV + v) * 128 + l15;
#pragma unroll
                    for (int n = 0; n < 8; ++n)
                        mp[n * 16] = f2bf(fmaxf(fmaf(aO[n], acc[n][j], bO[n]), 0.f));
                }
            }
        } else if (MODE == 0) {
            float aO[8], bO[8];
#pragma unroll
            for (int n = 0; n < 8; ++n) {
                const int cl = n * 16 + l15;
                aO[n] = aB[(z - 1) * 128 + cl]; bO[n] = bB[(z - 1) * 128 + cl];
            }
            const int vbase = v0 + wid * 16 + l4 * 4;
#pragma unroll
            for (int n = 0; n < 8; ++n) {
                const int cl = n * 16 + l15;
                const int ch = (z - 1) * 128 + cl;
                ushort* p = x2Out + ((size_t)b * 256 + ch) * NVV + vbase;
                if (vbase + 4 <= NVV) {
                    uint* pu = (uint*)p;
                    pu[0] = pack2(fmaf(aO[n], acc[n][0], bO[n]),
                                  fmaf(aO[n], acc[n][1], bO[n]));
                    pu[1] = pack2(fmaf(aO[n], acc[n][2], bO[n]),
                                  fmaf(aO[n], acc[n][3], bO[n]));
                } else {
#pragma unroll
                    for (int j = 0; j < 4; ++j)
                        if (vbase + j < NVV)
                            p[j] = f2bf(fmaf(aO[n], acc[n][j], bO[n]));
                }
            }
        } else {
            float ss[8], sq[8];
#pragma unroll
            for (int n = 0; n < 8; ++n) { ss[n] = 0.f; sq[n] = 0.f; }
            const int vbase = v0 + wid * 16 + l4 * 4;
#pragma unroll
            for (int n = 0; n < 8; ++n) {
                const int cl = n * 16 + l15;
                const int ch = z * 128 + cl;
                ushort* p = x1Out + ((size_t)b * 256 + ch) * NVV + vbase;
                if (vbase + 4 <= NVV) {
                    float v0f = acc[n][0], v1f = acc[n][1];
                    float v2f = acc[n][2], v3f = acc[n][3];
                    uint* pu = (uint*)p;
                    pu[0] = pack2(v0f, v1f);
                    pu[1] = pack2(v2f, v3f);
                    ss[n] += v0f + v1f + v2f + v3f;
                    sq[n] = fmaf(v0f, v0f, sq[n]); sq[n] = fmaf(v1f, v1f, sq[n]);
                    sq[n] = fmaf(v2f, v2f, sq[n]); sq[n] = fmaf(v3f, v3f, sq[n]);
                } else {
#pragma unroll
                    for (int j = 0; j < 4; ++j) {
                        if (vbase + j < NVV) {
                            const float val = acc[n][j];
                            p[j] = f2bf(val);
                            ss[n] += val;
                            sq[n] = fmaf(val, val, sq[n]);
                        }
                    }
                }
            }
#pragma unroll
            for (int n = 0; n < 8; ++n) {
                ss[n] += __shfl_xor(ss[n], 16); ss[n] += __shfl_xor(ss[n], 32);
                sq[n] += __shfl_xor(sq[n], 16); sq[n] += __shfl_xor(sq[n], 32);
            }
            __syncthreads();   // Bs (aliased by stats) fully dead after MFMA phase
            if (l < 16) {
#pragma unroll
                for (int n = 0; n < 8; ++n) {
                    statS[wid * 128 + n * 16 + l] = ss[n];
                    statQ[wid * 128 + n * 16 + l] = sq[n];
                }
            }
            __syncthreads();
            if (t < 128) {
                const int slot = b * 161 + vblk;
                statSum[((size_t)z * 1288 + slot) * 128 + t] =
                    statS[t] + statS[128 + t] + statS[256 + t] + statS[384 + t];
                statSsq[((size_t)z * 1288 + slot) * 128 + t] =
                    statQ[t] + statQ[128 + t] + statQ[256 + t] + statQ[384 + t];
            }
            __syncthreads();
        }
    }
}

// ---------------------------------------------------------------------------
// face_gemm v2: gface[f] = gf_ew[f]*C2 + gf_ns[f]*C3 (K=256 MFMA GEMM).
// Re-phased staging: only one channel-half's [ew|ns] pair live at a time.
// LDS: Fg[2][64*64] (16KB) + Bs (16KB) + meta (~7KB) = 39.7KB -> 4 blk/CU.
// Grid 2560; b = bid&7 (XCD-pinned).
// ---------------------------------------------------------------------------
__global__ __launch_bounds__(256)
void face_gemm_kernel(const ushort* __restrict__ h, const uint4* __restrict__ fBpk,
                      const float* __restrict__ Gv, const int* __restrict__ Gc,
                      const float* __restrict__ EW, const float* __restrict__ NSm,
                      ushort* __restrict__ gface)
{
    __shared__ __align__(16) ushort Fg[2][64 * 64];
    __shared__ __align__(16) ushort Bs[128 * 64];
    __shared__ int   colS[576];
    __shared__ float weS[576];
    __shared__ float wnS[576];
    const int t = threadIdx.x;
    const int bid = blockIdx.x;
    const int b = bid & 7;
    const int f0 = (bid >> 3) * 64;
    const int l = t & 63, wid = t >> 6;
    const int l15 = l & 15, l4 = l >> 4;
    const ushort* hb = h + (size_t)b * NVV * 128;

    for (int i = t; i < 576; i += 256) {
        const int r = i / 9, m = i - r * 9;
        const int e = m / 3, jj = m - e * 3;
        const int f = f0 + r;
        const size_t gidx = ((size_t)e * NFF + f) * 3 + jj;
        const float g = Gv[gidx];
        colS[i] = Gc[gidx];
        weS[i] = EW[f * 3 + e] * g;
        wnS[i] = NSm[f * 3 + e] * g;
    }
    __syncthreads();

    f32x4_t acc[8];
#pragma unroll
    for (int n = 0; n < 8; ++n) acc[n] = (f32x4_t){0.f, 0.f, 0.f, 0.f};

    for (int ch = 0; ch < 2; ++ch) {
        // ---- stage: 512 items = 64 faces x 8 pieces, shared ew/ns gathers ----
#pragma unroll
        for (int it = 0; it < 2; ++it) {
            const int idx = t + (it << 8);
            const int r = idx >> 3, p = idx & 7;
            const int cb = ch * 64 + p * 8;
            float se[8] = {0.f, 0.f, 0.f, 0.f, 0.f, 0.f, 0.f, 0.f};
            float sn[8] = {0.f, 0.f, 0.f, 0.f, 0.f, 0.f, 0.f, 0.f};
#pragma unroll
            for (int m = 0; m < 9; ++m) {
                const int col = colS[r * 9 + m];
                const uint4 hv = *reinterpret_cast<const uint4*>(hb + (size_t)col * 128 + cb);
                fma8x2(hv, weS[r * 9 + m], wnS[r * 9 + m], se, sn);
            }
            const int byte = (r << 7) + (p << 4);
            const int swz = byte ^ ((r & 7) << 4);
            *reinterpret_cast<uint4*>((char*)Fg[0] + swz) = pack8(se);
            *reinterpret_cast<uint4*>((char*)Fg[1] + swz) = pack8(sn);
        }
        __syncthreads();
        // ---- GEMM the two K-chunks (ew: chunk=ch, ns: chunk=2+ch) ----
        for (int half = 0; half < 2; ++half) {
            const int chunk = half * 2 + ch;
#pragma unroll
            for (int i = 0; i < 4; ++i)
                reinterpret_cast<uint4*>(Bs)[t + (i << 8)] = fBpk[chunk * 1024 + t + (i << 8)];
            __syncthreads();
#pragma unroll
            for (int kk2 = 0; kk2 < 2; ++kk2) {
                const int row = wid * 16 + l15;
                const int abyte = (row << 7) + (kk2 << 6) + (l4 << 4);
                const bf16x8_t af = *reinterpret_cast<const bf16x8_t*>(
                    (const char*)Fg[half] + (abyte ^ ((row & 7) << 4)));
#pragma unroll
                for (int n = 0; n < 8; ++n) {
                    const int o = n * 16 + l15;
                    const int bbyte = (o << 7) + (kk2 << 6) + (l4 << 4);
                    const bf16x8_t bfr = *reinterpret_cast<const bf16x8_t*>(
                        (const char*)Bs + (bbyte ^ ((o & 7) << 4)));
                    acc[n] = __builtin_amdgcn_mfma_f32_16x16x32_bf16(af, bfr, acc[n], 0, 0, 0);
                }
            }
            __syncthreads();
        }
    }

#pragma unroll
    for (int j = 0; j < 4; ++j) {
        const int r = wid * 16 + l4 * 4 + j;
        const int f = f0 + r;
        ushort* gp = gface + ((size_t)b * NFF + f) * 128 + l15;
#pragma unroll
        for (int n = 0; n < 8; ++n)
            gp[n * 16] = f2bf(acc[n][j]);
    }
}

// ---------------------------------------------------------------------------
// mesh_gemm, 64-row blocks, 6 chunks: q0=id (C0), q1=lap (C1), q2=gfc (B=I).
// Grid 1288; b = bid&7 (XCD-pinned), vblk = bid>>3. Stats aliased into Bs.
// ---------------------------------------------------------------------------
__global__ __launch_bounds__(256)
void mesh_gemm_kernel(const ushort* __restrict__ h, const ushort* __restrict__ gface,
                      const uint4* __restrict__ cpk,
                      const float* __restrict__ Lv, const int* __restrict__ Lc,
                      const float* __restrict__ Fv, const int* __restrict__ Fc,
                      ushort* __restrict__ meshraw,
                      float* __restrict__ msum, float* __restrict__ mssq)
{
    __shared__ __align__(16) ushort As[64 * 64];
    __shared__ __align__(16) ushort Bs[128 * 64];
    float* statS = (float*)Bs;
    float* statQ = (float*)Bs + 512;
    __shared__ int   LciS[448];
    __shared__ float LwS[448];
    __shared__ int   FciS[384];
    __shared__ float FwS[384];
    const int t = threadIdx.x;
    const int bid = blockIdx.x;
    const int b = bid & 7;
    const int vblk = bid >> 3;
    const int v0 = vblk * 64;
    const int l = t & 63, wid = t >> 6;
    const int l15 = l & 15, l4 = l >> 4;
    const size_t hb = (size_t)b * NVV * 128;

    for (int i = t; i < 448; i += 256) {
        const int g = v0 * 7 + i;
        if (g < NVV * 7) { LciS[i] = Lc[g]; LwS[i] = Lv[g]; }
    }
    for (int i = t; i < 384; i += 256) {
        const int g = v0 * 6 + i;
        if (g < NVV * 6) { FciS[i] = Fc[g]; FwS[i] = Fv[g]; }
    }
    __syncthreads();

    f32x4_t acc[8];
#pragma unroll
    for (int n = 0; n < 8; ++n) acc[n] = (f32x4_t){0.f, 0.f, 0.f, 0.f};

    for (int chunk = 0; chunk < 6; ++chunk) {
        const int q = chunk >> 1, c0 = (chunk & 1) << 6;
#pragma unroll
        for (int i = 0; i < 2; ++i) {
            const int item = t + (i << 8);
            const int r = item >> 3, piece = item & 7;
            const int cb = c0 + piece * 8;
            const int v = v0 + r;
            uint4 pk = make_uint4(0u, 0u, 0u, 0u);
            if (v < NVV) {
                if (q == 0) {
                    pk = *reinterpret_cast<const uint4*>(h + hb + (size_t)v * 128 + cb);
                } else if (q == 1) {
                    float s[8] = {0.f, 0.f, 0.f, 0.f, 0.f, 0.f, 0.f, 0.f};
#pragma unroll
                    for (int j = 0; j < 7; ++j) {
                        const float w = LwS[r * 7 + j];
                        const int col = LciS[r * 7 + j];
                        const uint4 hv = *reinterpret_cast<const uint4*>(h + hb + (size_t)col * 128 + cb);
                        fma8(hv, w, s);
                    }
                    pk = pack8(s);
                } else {
                    float s[8] = {0.f, 0.f, 0.f, 0.f, 0.f, 0.f, 0.f, 0.f};
#pragma unroll
                    for (int j = 0; j < 6; ++j) {
                        const float w = FwS[r * 6 + j];
                        const int f = FciS[r * 6 + j];
                        const uint4 gv = *reinterpret_cast<const uint4*>(
                            gface + ((size_t)b * NFF + f) * 128 + cb);
                        fma8(gv, w, s);
                    }
                    pk = pack8(s);
                }
            }
            const int byte = (r << 7) + (piece << 4);
            *reinterpret_cast<uint4*>((char*)As + (byte ^ ((r & 7) << 4))) = pk;
        }
#pragma unroll
        for (int i = 0; i < 4; ++i) {
            const int idx = t + (i << 8);
            reinterpret_cast<uint4*>(Bs)[idx] = cpk[chunk * 1024 + idx];
        }
        __syncthreads();
#pragma unroll
        for (int kk2 = 0; kk2 < 2; ++kk2) {
            const int row = wid * 16 + l15;
            const int abyte = (row << 7) + (kk2 << 6) + (l4 << 4);
            const bf16x8_t af = *reinterpret_cast<const bf16x8_t*>(
                (const char*)As + (abyte ^ ((row & 7) << 4)));
#pragma unroll
            for (int n = 0; n < 8; ++n) {
                const int o = n * 16 + l15;
                const int bbyte = (o << 7) + (kk2 << 6) + (l4 << 4);
                const bf16x8_t bfr = *reinterpret_cast<const bf16x8_t*>(
                    (const char*)Bs + (bbyte ^ ((o & 7) << 4)));
                acc[n] = __builtin_amdgcn_mfma_f32_16x16x32_bf16(af, bfr, acc[n], 0, 0, 0);
            }
        }
        __syncthreads();
    }
    // ---- epilogue: meshraw bf16 + per-channel stats ----
    float ss[8], sq[8];
#pragma unroll
    for (int n = 0; n < 8; ++n) { ss[n] = 0.f; sq[n] = 0.f; }
#pragma unroll
    for (int j = 0; j < 4; ++j) {
        const int row = wid * 16 + l4 * 4 + j;
        const int v = v0 + row;
        if (v < NVV) {
            ushort* mp = meshraw + hb + (size_t)v * 128 + l15;
#pragma unroll
            for (int n = 0; n < 8; ++n) {
                const float val = acc[n][j];
                mp[n * 16] = f2bf(val);
                ss[n] += val;
                sq[n] = fmaf(val, val, sq[n]);
            }
        }
    }
#pragma unroll
    for (int n = 0; n < 8; ++n) {
        ss[n] += __shfl_xor(ss[n], 16); ss[n] += __shfl_xor(ss[n], 32);
        sq[n] += __shfl_xor(sq[n], 16); sq[n] += __shfl_xor(sq[n], 32);
    }
    __syncthreads();   // Bs (aliased by stats) dead after last MFMA
    if (l < 16) {
#pragma unroll
        for (int n = 0; n < 8; ++n) {
            statS[wid * 128 + n * 16 + l] = ss[n];
            statQ[wid * 128 + n * 16 + l] = sq[n];
        }
    }
    __syncthreads();
    if (t < 128) {
        const int blk = b * 161 + vblk;
        msum[(size_t)blk * 128 + t] = statS[t] + statS[128 + t] + statS[256 + t] + statS[384 + t];
        mssq[(size_t)blk * 128 + t] = statQ[t] + statQ[128 + t] + statQ[256 + t] + statQ[384 + t];
    }
}

// ---------------------------------------------------------------------------
__global__ __launch_bounds__(256)
void finalize_stats_kernel(const float* __restrict__ s, const float* __restrict__ q, int count,
                           const float* __restrict__ g, const float* __restrict__ be,
                           float* __restrict__ alpha, float* __restrict__ beta, int split)
{
    const int c = blockIdx.x, t = threadIdx.x;
    const size_t base = split ? ((size_t)(c >> 7) * count * 128 + (c & 127)) : (size_t)c;
    float ls = 0.f, lq = 0.f;
    for (int i = t; i < count; i += 256) {
        ls += s[base + (size_t)i * 128];
        lq += q[base + (size_t)i * 128];
    }
    __shared__ float rs[256], rq[256];
    rs[t] = ls; rq[t] = lq;
    __syncthreads();
    for (int off = 128; off > 0; off >>= 1) {
        if (t < off) { rs[t] += rs[t + off]; rq[t] += rq[t + off]; }
        __syncthreads();
    }
    if (t == 0) {
        const float invN = 1.f / (float)(BB * NVV);
        const float mean = rs[0] * invN;
        const float var = rq[0] * invN - mean * mean;
        const float a = g[c] * rsqrtf(var + EPSBN);
        alpha[c] = a;
        beta[c] = be[c] - a * mean;
    }
}

// ---------------------------------------------------------------------------
// K8: out = relu(alpha3*x1 + beta3 + x2)   (x1, x2 bf16 -> out fp32)
// ---------------------------------------------------------------------------
__global__ __launch_bounds__(256)
void final_kernel(float* __restrict__ out, const ushort* __restrict__ x1,
                  const ushort* __restrict__ x2,
                  const float* __restrict__ alpha3, const float* __restrict__ beta3)
{
    const int blk = blockIdx.x;
    const int o = blk & 255;
    const float a = alpha3[o], bb = beta3[o];
    float2* po = reinterpret_cast<float2*>(out + (size_t)blk * NVV);
    const uint* p1 = reinterpret_cast<const uint*>(x1 + (size_t)blk * NVV);
    const uint* p2 = reinterpret_cast<const uint*>(x2 + (size_t)blk * NVV);
    for (int i = threadIdx.x; i < NVV / 2; i += 256) {
        float a1, b1, a2, b2;
        unpack2(p1[i], a1, b1);
        unpack2(p2[i], a2, b2);
        po[i] = make_float2(fmaxf(fmaf(a, a1, bb) + a2, 0.f),
                            fmaxf(fmaf(a, b1, bb) + b2, 0.f));
    }
}

// ---------------------------------------------------------------------------
extern "C" void kernel_launch(void* const* d_in, const int* in_sizes, int n_in,
                              void* d_out, int out_size, void* d_ws, size_t ws_size,
                              hipStream_t stream)
{
    (void)in_sizes; (void)n_in; (void)out_size;
    const float* x      = (const float*)d_in[0];
    const float* w1a    = (const float*)d_in[1];
    const float* g1a    = (const float*)d_in[3];
    const float* be1a   = (const float*)d_in[4];
    const float* coeffs = (const float*)d_in[5];
    const float* g2a    = (const float*)d_in[6];
    const float* be2a   = (const float*)d_in[7];
    const float* w3a    = (const float*)d_in[8];
    const float* g3a    = (const float*)d_in[10];
    const float* be3a   = (const float*)d_in[11];
    const float* w1b    = (const float*)d_in[12];
    const float* g1b    = (const float*)d_in[14];
    const float* be1b   = (const float*)d_in[15];
    const float* Gv     = (const float*)d_in[16];
    const float* Lv     = (const float*)d_in[17];
    const float* Fv     = (const float*)d_in[18];
    const float* EW     = (const float*)d_in[19];
    const float* NSm    = (const float*)d_in[20];
    const int*   Gc     = (const int*)d_in[22];
    const int*   Lc     = (const int*)d_in[24];
    const int*   Fc     = (const int*)d_in[26];

    char* base = (char*)d_ws;
    size_t off = 0;
    auto alloc = [&](size_t bytes) { char* p = base + off; off += (bytes + 255) & ~(size_t)255; return p; };

    // region0 timeline: gramPart+xsumPart -> gface (face/mesh) -> x1 (conv3/final)
    const size_t r0Bytes = (size_t)GRAM_BLOCKS * 16384 * 4 + (size_t)GRAM_BLOCKS * 128 * 4 + 4096;
    char* region0   = alloc(r0Bytes);
    float* gramPart = (float*)region0;
    float* xsumPart = (float*)(region0 + (size_t)GRAM_BLOCKS * 16384 * 4);
    ushort* gface   = (ushort*)region0;                           // 41.9 MB
    ushort* x1      = (ushort*)region0;                           // after gface dead

    ushort* xT      = (ushort*)alloc((size_t)BB * NVV * 128 * 2);
    ushort* h       = (ushort*)alloc((size_t)BB * NVV * 128 * 2);
    ushort* meshraw = (ushort*)alloc((size_t)BB * NVV * 128 * 2);
    ushort* x2      = (ushort*)alloc((size_t)BB * 256 * NVV * 2);
    uint*  cpk      = (uint*)alloc(40960 * 4);
    uint*  wpk      = (uint*)alloc(40960 * 4);
    float* Gram     = (float*)alloc(16384 * 4);
    float* xsum     = (float*)alloc(128 * 4);
    float* alpha_a  = (float*)alloc(128 * 4);
    float* beta_a   = (float*)alloc(128 * 4);
    float* alpha_b  = (float*)alloc(256 * 4);
    float* beta_b   = (float*)alloc(256 * 4);
    float* alpha2   = (float*)alloc(128 * 4);
    float* beta2    = (float*)alloc(128 * 4);
    float* alpha3   = (float*)alloc(256 * 4);
    float* beta3    = (float*)alloc(256 * 4);
    float* msum     = (float*)alloc((size_t)1288 * 128 * 4);
    float* mssq     = (float*)alloc((size_t)1288 * 128 * 4);
    float* x1sum    = (float*)alloc((size_t)2 * 1288 * 128 * 4);
    float* x1ssq    = (float*)alloc((size_t)2 * 1288 * 128 * 4);
    if (off > ws_size) return;   // fail loud (validation will catch)

    gram_kernel<<<GRAM_BLOCKS, 256, 0, stream>>>(x, gramPart, xsumPart, (uint*)xT);
    reduce_gram_kernel<<<64, 256, 0, stream>>>(gramPart, xsumPart, Gram, xsum);
    stats_ab_kernel<<<384, 128, 0, stream>>>(Gram, xsum, w1a, g1a, be1a, w1b, g1b, be1b,
                                             alpha_a, beta_a, alpha_b, beta_b);
    prepack_coeffs_kernel<<<160, 256, 0, stream>>>(coeffs, cpk);
    prepack_weights_kernel<<<160, 256, 0, stream>>>(w1a, w1b, w3a, wpk);
    mfma_conv_kernel<0><<<1288, 256, 0, stream>>>(
        xT, (const uint4*)wpk, nullptr, nullptr, alpha_a, beta_a, alpha_b, beta_b,
        h, x2, nullptr, nullptr, nullptr);
    face_gemm_kernel<<<(NFF / 64) * 8, 256, 0, stream>>>(
        h, (const uint4*)cpk + 6 * 1024, Gv, Gc, EW, NSm, gface);
    mesh_gemm_kernel<<<1288, 256, 0, stream>>>(h, gface, (const uint4*)cpk,
                                               Lv, Lc, Fv, Fc, meshraw, msum, mssq);
    finalize_stats_kernel<<<128, 256, 0, stream>>>(msum, mssq, 1288, g2a, be2a, alpha2, beta2, 0);
    mfma_conv_kernel<1><<<1288, 256, 0, stream>>>(
        meshraw, (const uint4*)wpk, alpha2, beta2, nullptr, nullptr, nullptr, nullptr,
        nullptr, nullptr, x1, x1sum, x1ssq);
    finalize_stats_kernel<<<256, 256, 0, stream>>>(x1sum, x1ssq, 1288, g3a, be3a, alpha3, beta3, 1);
    final_kernel<<<2048, 256, 0, stream>>>((float*)d_out, x1, x2, alpha3, beta3);
}

// Round 13
// 269.718 us; speedup vs baseline: 1.0872x; 1.0872x over previous
//
#include <hip/hip_runtime.h>
#include <math.h>

#define BB   8
#define NVV  10242
#define NFF  20480
#define EPSBN 1e-5f
#define GRAM_BLOCKS 644   // x 2 chunks each = 1288 = 8 batches * 161 vert-chunks

typedef __attribute__((ext_vector_type(8))) short bf16x8_t;
typedef __attribute__((ext_vector_type(4))) float f32x4_t;

__device__ inline float bf2f(ushort u) {
    union { uint i; float f; } v; v.i = ((uint)u) << 16; return v.f;
}
__device__ inline ushort f2bf(float f) {
    union { float f; uint i; } v; v.f = f;
    const uint r = v.i + 0x7fffu + ((v.i >> 16) & 1u);
    return (ushort)(r >> 16);
}
__device__ inline void unpack2(uint w, float& lo, float& hi) {
    union { uint i; float f; } a, b;
    a.i = w << 16; b.i = w & 0xffff0000u;
    lo = a.f; hi = b.f;
}
__device__ inline uint pack2(float lo, float hi) {
    return (uint)f2bf(lo) | ((uint)f2bf(hi) << 16);
}
__device__ inline void fma8(const uint4 hv, const float w, float s[8]) {
    float lo, hi;
    unpack2(hv.x, lo, hi); s[0] = fmaf(w, lo, s[0]); s[1] = fmaf(w, hi, s[1]);
    unpack2(hv.y, lo, hi); s[2] = fmaf(w, lo, s[2]); s[3] = fmaf(w, hi, s[3]);
    unpack2(hv.z, lo, hi); s[4] = fmaf(w, lo, s[4]); s[5] = fmaf(w, hi, s[5]);
    unpack2(hv.w, lo, hi); s[6] = fmaf(w, lo, s[6]); s[7] = fmaf(w, hi, s[7]);
}
__device__ inline void fma8x2(const uint4 hv, const float wa, const float wb,
                              float sa[8], float sb[8]) {
    float lo, hi;
    unpack2(hv.x, lo, hi);
    sa[0] = fmaf(wa, lo, sa[0]); sb[0] = fmaf(wb, lo, sb[0]);
    sa[1] = fmaf(wa, hi, sa[1]); sb[1] = fmaf(wb, hi, sb[1]);
    unpack2(hv.y, lo, hi);
    sa[2] = fmaf(wa, lo, sa[2]); sb[2] = fmaf(wb, lo, sb[2]);
    sa[3] = fmaf(wa, hi, sa[3]); sb[3] = fmaf(wb, hi, sb[3]);
    unpack2(hv.z, lo, hi);
    sa[4] = fmaf(wa, lo, sa[4]); sb[4] = fmaf(wb, lo, sb[4]);
    sa[5] = fmaf(wa, hi, sa[5]); sb[5] = fmaf(wb, hi, sb[5]);
    unpack2(hv.w, lo, hi);
    sa[6] = fmaf(wa, lo, sa[6]); sb[6] = fmaf(wb, lo, sb[6]);
    sa[7] = fmaf(wa, hi, sa[7]); sb[7] = fmaf(wb, hi, sb[7]);
}
__device__ inline uint4 pack8(const float s[8]) {
    uint4 p;
    p.x = pack2(s[0], s[1]); p.y = pack2(s[2], s[3]);
    p.z = pack2(s[4], s[5]); p.w = pack2(s[6], s[7]);
    return p;
}

// ---------------------------------------------------------------------------
// K0: Gram partials via MFMA bf16 hi/lo split + xsum partials + xT bf16 write.
// ---------------------------------------------------------------------------
__global__ __launch_bounds__(256)
void gram_kernel(const float* __restrict__ x, float* __restrict__ gramPart,
                 float* __restrict__ xsumPart, uint* __restrict__ xTu)
{
    __shared__ __align__(16) ushort Ahi[128 * 64];
    __shared__ __align__(16) ushort Alo[128 * 64];
    const int t = threadIdx.x;
    const int l = t & 63, wid = t >> 6;
    const int l15 = l & 15, l4 = l >> 4;
    f32x4_t acc[2][8];
#pragma unroll
    for (int m = 0; m < 2; ++m)
#pragma unroll
        for (int n = 0; n < 8; ++n) acc[m][n] = (f32x4_t){0.f, 0.f, 0.f, 0.f};
    float xs[8] = {0.f, 0.f, 0.f, 0.f, 0.f, 0.f, 0.f, 0.f};

    for (int s = 0; s < 2; ++s) {
        const int cc = blockIdx.x * 2 + s;
        const int b = cc / 161, tb = cc % 161, v0 = tb * 64;
#pragma unroll
        for (int i = 0; i < 8; ++i) {
            const int item = t + (i << 8);
            const int c = item >> 4, vq = item & 15;
            const int gv = v0 + (vq << 2);
            const float* xp = x + ((size_t)b * 128 + c) * NVV + gv;
            float4 xv = make_float4(0.f, 0.f, 0.f, 0.f);
            if (gv + 4 <= NVV) {
                xv = *reinterpret_cast<const float4*>(xp);
            } else {
                if (gv     < NVV) xv.x = xp[0];
                if (gv + 1 < NVV) xv.y = xp[1];
            }
            xs[i] += xv.x + xv.y + xv.z + xv.w;
            const ushort h0 = f2bf(xv.x), h1 = f2bf(xv.y), h2 = f2bf(xv.z), h3 = f2bf(xv.w);
            const ushort e0 = f2bf(xv.x - bf2f(h0)), e1 = f2bf(xv.y - bf2f(h1));
            const ushort e2 = f2bf(xv.z - bf2f(h2)), e3 = f2bf(xv.w - bf2f(h3));
            uint2 hp, lp;
            hp.x = (uint)h0 | ((uint)h1 << 16); hp.y = (uint)h2 | ((uint)h3 << 16);
            lp.x = (uint)e0 | ((uint)e1 << 16); lp.y = (uint)e2 | ((uint)e3 << 16);
            const int byte = (c << 7) + (vq << 3);
            const int swz = byte ^ ((c & 7) << 4);
            *reinterpret_cast<uint2*>((char*)Ahi + swz) = hp;
            *reinterpret_cast<uint2*>((char*)Alo + swz) = lp;
        }
        __syncthreads();
        {
            const int v = t & 63, cq = t >> 6;
            const int gv = v0 + v;
            if (gv < NVV) {
                uint4* rowp = reinterpret_cast<uint4*>(xTu + ((size_t)b * NVV + gv) * 64) + (cq << 2);
#pragma unroll
                for (int k2 = 0; k2 < 4; ++k2) {
                    uint wrd[4];
#pragma unroll
                    for (int w2 = 0; w2 < 4; ++w2) {
                        const int c0 = (cq << 5) + (k2 << 3) + (w2 << 1);
                        const int b0 = ((c0) << 7) + (v << 1);
                        const int b1 = ((c0 + 1) << 7) + (v << 1);
                        const ushort q0 = *reinterpret_cast<const ushort*>((const char*)Ahi + (b0 ^ ((c0 & 7) << 4)));
                        const ushort q1 = *reinterpret_cast<const ushort*>((const char*)Ahi + (b1 ^ (((c0 + 1) & 7) << 4)));
                        wrd[w2] = (uint)q0 | ((uint)q1 << 16);
                    }
                    rowp[k2] = make_uint4(wrd[0], wrd[1], wrd[2], wrd[3]);
                }
            }
        }
#pragma unroll
        for (int kk2 = 0; kk2 < 2; ++kk2) {
            bf16x8_t ah[2], al[2];
#pragma unroll
            for (int m = 0; m < 2; ++m) {
                const int row = wid * 32 + m * 16 + l15;
                const int byte = (row << 7) + (kk2 << 6) + (l4 << 4);
                ah[m] = *reinterpret_cast<const bf16x8_t*>((const char*)Ahi + (byte ^ ((row & 7) << 4)));
                al[m] = *reinterpret_cast<const bf16x8_t*>((const char*)Alo + (byte ^ ((row & 7) << 4)));
            }
#pragma unroll
            for (int n = 0; n < 8; ++n) {
                const int rn = n * 16 + l15;
                const int byte = (rn << 7) + (kk2 << 6) + (l4 << 4);
                const bf16x8_t bh = *reinterpret_cast<const bf16x8_t*>((const char*)Ahi + (byte ^ ((rn & 7) << 4)));
                const bf16x8_t bl = *reinterpret_cast<const bf16x8_t*>((const char*)Alo + (byte ^ ((rn & 7) << 4)));
#pragma unroll
                for (int m = 0; m < 2; ++m) {
                    acc[m][n] = __builtin_amdgcn_mfma_f32_16x16x32_bf16(ah[m], bh, acc[m][n], 0, 0, 0);
                    acc[m][n] = __builtin_amdgcn_mfma_f32_16x16x32_bf16(ah[m], bl, acc[m][n], 0, 0, 0);
                    acc[m][n] = __builtin_amdgcn_mfma_f32_16x16x32_bf16(al[m], bh, acc[m][n], 0, 0, 0);
                }
            }
        }
        __syncthreads();
    }
    float* gp = gramPart + (size_t)blockIdx.x * 16384;
#pragma unroll
    for (int m = 0; m < 2; ++m)
#pragma unroll
        for (int n = 0; n < 8; ++n)
#pragma unroll
            for (int j = 0; j < 4; ++j) {
                const int row = wid * 32 + m * 16 + l4 * 4 + j;
                const int col = n * 16 + l15;
                gp[row * 128 + col] = acc[m][n][j];
            }
#pragma unroll
    for (int i = 0; i < 8; ++i) {
        xs[i] += __shfl_xor(xs[i], 1);
        xs[i] += __shfl_xor(xs[i], 2);
        xs[i] += __shfl_xor(xs[i], 4);
        xs[i] += __shfl_xor(xs[i], 8);
    }
    if ((l & 15) == 0) {
#pragma unroll
        for (int i = 0; i < 8; ++i)
            xsumPart[(size_t)blockIdx.x * 128 + wid * 4 + l4 + i * 16] = xs[i];
    }
}

__global__ void reduce_gram_kernel(const float* __restrict__ gp, const float* __restrict__ xp,
                                   float* __restrict__ Gram, float* __restrict__ xsum)
{
    const int tid = blockIdx.x * 256 + threadIdx.x;
    for (int e = tid; e < 16384; e += 64 * 256) {
        float s = 0.f;
        for (int i = 0; i < GRAM_BLOCKS; ++i) s += gp[(size_t)i * 16384 + e];
        Gram[e] = s;
    }
    if (blockIdx.x == 0 && threadIdx.x < 128) {
        float s = 0.f;
        for (int i = 0; i < GRAM_BLOCKS; ++i) s += xp[(size_t)i * 128 + threadIdx.x];
        xsum[threadIdx.x] = s;
    }
}

// ---------------------------------------------------------------------------
// K1: analytic BN folding for conv1a (128 ch) and conv1b (256 ch)
// ---------------------------------------------------------------------------
__global__ __launch_bounds__(128)
void stats_ab_kernel(const float* __restrict__ Gram, const float* __restrict__ xsum,
                     const float* __restrict__ w1a, const float* __restrict__ g1a,
                     const float* __restrict__ be1a,
                     const float* __restrict__ w1b, const float* __restrict__ g1b,
                     const float* __restrict__ be1b,
                     float* __restrict__ alpha_a, float* __restrict__ beta_a,
                     float* __restrict__ alpha_b, float* __restrict__ beta_b)
{
    const int t = threadIdx.x;
    const int cc = blockIdx.x;
    const float invN = 1.f / (float)(BB * NVV);
    const bool isA = cc < 128;
    const int c = isA ? cc : cc - 128;
    const float* Wrow = isA ? (w1a + (size_t)c * 128) : (w1b + (size_t)c * 128);
    __shared__ float Wr[128];
    __shared__ float red[4];
    Wr[t] = Wrow[t];
    __syncthreads();
    float gi = 0.f;
    const float* Grow = Gram + (size_t)t * 128;
    for (int j = 0; j < 128; ++j) gi = fmaf(Grow[j], Wr[j], gi);
    float pi = Wr[t] * gi * invN;
    float qi = (xsum[t] * invN) * Wr[t];
    for (int off = 32; off > 0; off >>= 1) {
        pi += __shfl_down(pi, off);
        qi += __shfl_down(qi, off);
    }
    const int wid = t >> 6;
    if ((t & 63) == 0) { red[wid] = pi; red[2 + wid] = qi; }
    __syncthreads();
    if (t == 0) {
        const float P = red[0] + red[1], Q = red[2] + red[3];
        const float var = P - Q * Q;
        const float g = isA ? g1a[c] : g1b[c];
        const float be = isA ? be1a[c] : be1b[c];
        const float a = g * rsqrtf(var + EPSBN);
        if (isA) { alpha_a[c] = a; beta_a[c] = be - a * Q; }
        else     { alpha_b[c] = a; beta_b[c] = be - a * Q; }
    }
}

// ---------------------------------------------------------------------------
// Prepack weights (fp32 -> bf16, swizzled LDS image). 5 slabs x 2 kc-chunks.
// ---------------------------------------------------------------------------
__global__ __launch_bounds__(256)
void prepack_weights_kernel(const float* __restrict__ w1a, const float* __restrict__ w1b,
                            const float* __restrict__ w3a, uint* __restrict__ wpk)
{
    const int j = blockIdx.x * 256 + threadIdx.x;       // 0..40959
    const int seg = j >> 12;                             // slab*2 + kcIdx
    const int slab = seg >> 1, kc = (seg & 1) << 6;
    const int u = j & 4095;
    const int o = u >> 5;
    const int inner = (u << 2) & 127;
    const int inner0 = inner ^ ((o & 7) << 4);
    const int kp = inner0 >> 2;
    const float* W;
    if (slab == 0)      W = w1a;
    else if (slab <= 2) W = w1b + (size_t)(slab - 1) * 128 * 128;
    else                W = w3a + (size_t)(slab - 3) * 128 * 128;
    const float2 wv = *reinterpret_cast<const float2*>(&W[(size_t)o * 128 + kc + 2 * kp]);
    wpk[j] = pack2(wv.x, wv.y);
}

// ---------------------------------------------------------------------------
// Prepack coeffs -> swizzled LDS images, 10 chunks x 4096 uints:
// chunks 0-3: mesh (q0=id -> C0, q1=lap -> C1) x c_half
// chunks 4-5: identity B for the gfc injection (per c_half)
// chunks 6-9: face GEMM B = [C2;C3] in 4 K-chunks of 64
// ---------------------------------------------------------------------------
__global__ __launch_bounds__(256)
void prepack_coeffs_kernel(const float* __restrict__ coeffs, uint* __restrict__ cpk)
{
    const int j = blockIdx.x * 256 + threadIdx.x;    // grid 160 -> 40960
    const int chunk = j >> 12, u = j & 4095;
    const int o = u >> 5;
    const int inner = (u << 2) & 127;
    const int inner0 = inner ^ ((o & 7) << 4);
    const int p = inner0 >> 2;                        // k pair (2p, 2p+1)
    float v0f, v1f;
    if (chunk < 4) {
        const int q = chunk >> 1, c0 = (chunk & 1) << 6;
        const int row0 = (c0 + 2 * p) * 4 + q;
        v0f = coeffs[(size_t)row0 * 128 + o];
        v1f = coeffs[(size_t)(row0 + 4) * 128 + o];
    } else if (chunk < 6) {
        const int c0 = (chunk - 4) << 6;
        v0f = (o == c0 + 2 * p) ? 1.f : 0.f;
        v1f = (o == c0 + 2 * p + 1) ? 1.f : 0.f;
    } else {
        const int kc = chunk - 6;
        const int kg0 = kc * 64 + 2 * p;
        const int row0 = (kg0 < 128) ? (kg0 * 4 + 2) : ((kg0 - 128) * 4 + 3);
        const int row1 = (kg0 + 1 < 128) ? ((kg0 + 1) * 4 + 2) : ((kg0 + 1 - 128) * 4 + 3);
        v0f = coeffs[(size_t)row0 * 128 + o];
        v1f = coeffs[(size_t)row1 * 128 + o];
    }
    cpk[j] = pack2(v0f, v1f);
}

// ---------------------------------------------------------------------------
// Build face meta (batch-independent): colp[f*9+m], wp[f*9+m] = (EW*g, NS*g)
// m = e*3 + j.  NF*9 = 184320 entries.
// ---------------------------------------------------------------------------
__global__ __launch_bounds__(256)
void build_meta_kernel(const float* __restrict__ Gv, const int* __restrict__ Gc,
                       const float* __restrict__ EW, const float* __restrict__ NSm,
                       int* __restrict__ colp, float2* __restrict__ wp)
{
    const int i = blockIdx.x * 256 + threadIdx.x;
    if (i >= NFF * 9) return;
    const int f = i / 9, m = i - f * 9;
    const int e = m / 3, jj = m - e * 3;
    const size_t gidx = ((size_t)e * NFF + f) * 3 + jj;
    const float g = Gv[gidx];
    colp[i] = Gc[gidx];
    wp[i] = make_float2(EW[f * 3 + e] * g, NSm[f * 3 + e] * g);
}

// ---------------------------------------------------------------------------
// z-fused MFMA conv, 64-row blocks (stats aliased into Bs).
// ---------------------------------------------------------------------------
template <int MODE>
__global__ __launch_bounds__(256)
void mfma_conv_kernel(const ushort* __restrict__ Asrc, const uint4* __restrict__ wpk,
                      const float* __restrict__ aIn, const float* __restrict__ bIn,
                      const float* __restrict__ aA, const float* __restrict__ bA,
                      const float* __restrict__ aB, const float* __restrict__ bB,
                      ushort* __restrict__ hOut, ushort* __restrict__ x2Out,
                      ushort* __restrict__ x1Out,
                      float* __restrict__ statSum, float* __restrict__ statSsq)
{
    __shared__ __align__(16) ushort As[64 * 128];
    __shared__ __align__(16) ushort Bs[128 * 64];
    float* statS = (float*)Bs;            // aliased: Bs dead when stats used
    float* statQ = (float*)Bs + 512;
    const int t = threadIdx.x;
    const int bid = blockIdx.x;
    const int b = bid & 7, vblk = bid >> 3;
    const int v0 = vblk * 64;
    const int l = t & 63, wid = t >> 6;
    const int l15 = l & 15, l4 = l >> 4;

#pragma unroll
    for (int i = 0; i < 4; ++i) {
        const int item = t + (i << 8);
        const int r = item >> 4, piece = item & 15;
        const int cb = piece * 8;
        const int v = v0 + r;
        uint4 pk = make_uint4(0u, 0u, 0u, 0u);
        if (v < NVV) {
            pk = *reinterpret_cast<const uint4*>(Asrc + ((size_t)b * NVV + v) * 128 + cb);
            if (MODE == 1) {
                float s[8];
                unpack2(pk.x, s[0], s[1]); unpack2(pk.y, s[2], s[3]);
                unpack2(pk.z, s[4], s[5]); unpack2(pk.w, s[6], s[7]);
                const float4 a0 = *reinterpret_cast<const float4*>(&aIn[cb]);
                const float4 a1 = *reinterpret_cast<const float4*>(&aIn[cb + 4]);
                const float4 b0 = *reinterpret_cast<const float4*>(&bIn[cb]);
                const float4 b1 = *reinterpret_cast<const float4*>(&bIn[cb + 4]);
                s[0] = fmaxf(fmaf(a0.x, s[0], b0.x), 0.f);
                s[1] = fmaxf(fmaf(a0.y, s[1], b0.y), 0.f);
                s[2] = fmaxf(fmaf(a0.z, s[2], b0.z), 0.f);
                s[3] = fmaxf(fmaf(a0.w, s[3], b0.w), 0.f);
                s[4] = fmaxf(fmaf(a1.x, s[4], b1.x), 0.f);
                s[5] = fmaxf(fmaf(a1.y, s[5], b1.y), 0.f);
                s[6] = fmaxf(fmaf(a1.z, s[6], b1.z), 0.f);
                s[7] = fmaxf(fmaf(a1.w, s[7], b1.w), 0.f);
                pk = pack8(s);
            }
        }
        const int byte = (r << 8) + (piece << 4);
        *reinterpret_cast<uint4*>((char*)As + (byte ^ ((r & 7) << 4))) = pk;
    }

    const int NZ = (MODE == 0) ? 3 : 2;
    for (int z = 0; z < NZ; ++z) {
        const int slab = (MODE == 0) ? z : (3 + z);
        f32x4_t acc[8];
#pragma unroll
        for (int n = 0; n < 8; ++n) acc[n] = (f32x4_t){0.f, 0.f, 0.f, 0.f};

        for (int kc = 0; kc < 128; kc += 64) {
            const uint4* wseg = wpk + (size_t)(slab * 2 + (kc >> 6)) * 1024;
#pragma unroll
            for (int i = 0; i < 4; ++i)
                reinterpret_cast<uint4*>(Bs)[t + (i << 8)] = wseg[t + (i << 8)];
            __syncthreads();
#pragma unroll
            for (int kk2 = 0; kk2 < 2; ++kk2) {
                const int row = wid * 16 + l15;
                const int abyte = (row << 8) + (kc << 1) + (kk2 << 6) + (l4 << 4);
                const bf16x8_t af = *reinterpret_cast<const bf16x8_t*>(
                    (const char*)As + (abyte ^ ((row & 7) << 4)));
#pragma unroll
                for (int n = 0; n < 8; ++n) {
                    const int o = n * 16 + l15;
                    const int bbyte = (o << 7) + (kk2 << 6) + (l4 << 4);
                    const bf16x8_t bfr = *reinterpret_cast<const bf16x8_t*>(
                        (const char*)Bs + (bbyte ^ ((o & 7) << 4)));
                    acc[n] = __builtin_amdgcn_mfma_f32_16x16x32_bf16(af, bfr, acc[n], 0, 0, 0);
                }
            }
            __syncthreads();
        }

        if (MODE == 0 && z == 0) {
            float aO[8], bO[8];
#pragma unroll
            for (int n = 0; n < 8; ++n) {
                const int c = n * 16 + l15;
                aO[n] = aA[c]; bO[n] = bA[c];
            }
#pragma unroll
            for (int j = 0; j < 4; ++j) {
                const int v = v0 + wid * 16 + l4 * 4 + j;
                if (v < NVV) {
                    ushort* mp = hOut + ((size_t)b * NVV + v) * 128 + l15;
#pragma unroll
                    for (int n = 0; n < 8; ++n)
                        mp[n * 16] = f2bf(fmaxf(fmaf(aO[n], acc[n][j], bO[n]), 0.f));
                }
            }
        } else if (MODE == 0) {
            float aO[8], bO[8];
#pragma unroll
            for (int n = 0; n < 8; ++n) {
                const int cl = n * 16 + l15;
                aO[n] = aB[(z - 1) * 128 + cl]; bO[n] = bB[(z - 1) * 128 + cl];
            }
            const int vbase = v0 + wid * 16 + l4 * 4;
#pragma unroll
            for (int n = 0; n < 8; ++n) {
                const int cl = n * 16 + l15;
                const int ch = (z - 1) * 128 + cl;
                ushort* p = x2Out + ((size_t)b * 256 + ch) * NVV + vbase;
                if (vbase + 4 <= NVV) {
                    uint* pu = (uint*)p;
                    pu[0] = pack2(fmaf(aO[n], acc[n][0], bO[n]),
                                  fmaf(aO[n], acc[n][1], bO[n]));
                    pu[1] = pack2(fmaf(aO[n], acc[n][2], bO[n]),
                                  fmaf(aO[n], acc[n][3], bO[n]));
                } else {
#pragma unroll
                    for (int j = 0; j < 4; ++j)
                        if (vbase + j < NVV)
                            p[j] = f2bf(fmaf(aO[n], acc[n][j], bO[n]));
                }
            }
        } else {
            float ss[8], sq[8];
#pragma unroll
            for (int n = 0; n < 8; ++n) { ss[n] = 0.f; sq[n] = 0.f; }
            const int vbase = v0 + wid * 16 + l4 * 4;
#pragma unroll
            for (int n = 0; n < 8; ++n) {
                const int cl = n * 16 + l15;
                const int ch = z * 128 + cl;
                ushort* p = x1Out + ((size_t)b * 256 + ch) * NVV + vbase;
                if (vbase + 4 <= NVV) {
                    float v0f = acc[n][0], v1f = acc[n][1];
                    float v2f = acc[n][2], v3f = acc[n][3];
                    uint* pu = (uint*)p;
                    pu[0] = pack2(v0f, v1f);
                    pu[1] = pack2(v2f, v3f);
                    ss[n] += v0f + v1f + v2f + v3f;
                    sq[n] = fmaf(v0f, v0f, sq[n]); sq[n] = fmaf(v1f, v1f, sq[n]);
                    sq[n] = fmaf(v2f, v2f, sq[n]); sq[n] = fmaf(v3f, v3f, sq[n]);
                } else {
#pragma unroll
                    for (int j = 0; j < 4; ++j) {
                        if (vbase + j < NVV) {
                            const float val = acc[n][j];
                            p[j] = f2bf(val);
                            ss[n] += val;
                            sq[n] = fmaf(val, val, sq[n]);
                        }
                    }
                }
            }
#pragma unroll
            for (int n = 0; n < 8; ++n) {
                ss[n] += __shfl_xor(ss[n], 16); ss[n] += __shfl_xor(ss[n], 32);
                sq[n] += __shfl_xor(sq[n], 16); sq[n] += __shfl_xor(sq[n], 32);
            }
            __syncthreads();   // Bs (aliased by stats) fully dead after MFMA phase
            if (l < 16) {
#pragma unroll
                for (int n = 0; n < 8; ++n) {
                    statS[wid * 128 + n * 16 + l] = ss[n];
                    statQ[wid * 128 + n * 16 + l] = sq[n];
                }
            }
            __syncthreads();
            if (t < 128) {
                const int slot = b * 161 + vblk;
                statSum[((size_t)z * 1288 + slot) * 128 + t] =
                    statS[t] + statS[128 + t] + statS[256 + t] + statS[384 + t];
                statSsq[((size_t)z * 1288 + slot) * 128 + t] =
                    statQ[t] + statQ[128 + t] + statQ[256 + t] + statQ[384 + t];
            }
            __syncthreads();
        }
    }
}

// ---------------------------------------------------------------------------
// face_gemm v3: gface[f] = gf_ew[f]*C2 + gf_ns[f]*C3 (K=256 MFMA GEMM).
// Single-pass staging (r11 structure) but meta read DIRECTLY from prepacked
// global colp/wp (broadcast, L2-hot) -> no meta LDS, no meta barrier.
// LDS: Fg[4][64*64] (32KB) + Bs (16KB) = 49.2KB -> 3 blocks/CU.
// Grid 2560; b = bid&7 (XCD-pinned).
// ---------------------------------------------------------------------------
__global__ __launch_bounds__(256)
void face_gemm_kernel(const ushort* __restrict__ h, const uint4* __restrict__ fBpk,
                      const int* __restrict__ colp, const float2* __restrict__ wp,
                      ushort* __restrict__ gface)
{
    __shared__ __align__(16) ushort Fg[4][64 * 64];
    __shared__ __align__(16) ushort Bs[128 * 64];
    const int t = threadIdx.x;
    const int bid = blockIdx.x;
    const int b = bid & 7;
    const int f0 = (bid >> 3) * 64;
    const int l = t & 63, wid = t >> 6;
    const int l15 = l & 15, l4 = l >> 4;
    const ushort* hb = h + (size_t)b * NVV * 128;

#pragma unroll
    for (int it = 0; it < 4; ++it) {
        const int idx = t + (it << 8);
        const int r = idx >> 4, p = idx & 15;
        const int cb = p * 8;
        const int base = (f0 + r) * 9;
        float se[8] = {0.f, 0.f, 0.f, 0.f, 0.f, 0.f, 0.f, 0.f};
        float sn[8] = {0.f, 0.f, 0.f, 0.f, 0.f, 0.f, 0.f, 0.f};
#pragma unroll
        for (int m = 0; m < 9; ++m) {
            const int col = colp[base + m];
            const float2 w = wp[base + m];
            const uint4 hv = *reinterpret_cast<const uint4*>(hb + (size_t)col * 128 + cb);
            fma8x2(hv, w.x, w.y, se, sn);
        }
        const int ch = cb >> 6;
        const int piece = (cb & 63) >> 3;
        const int byte = (r << 7) + (piece << 4);
        const int swz = byte ^ ((r & 7) << 4);
        *reinterpret_cast<uint4*>((char*)Fg[ch] + swz)     = pack8(se);
        *reinterpret_cast<uint4*>((char*)Fg[2 + ch] + swz) = pack8(sn);
    }
    __syncthreads();

    f32x4_t acc[8];
#pragma unroll
    for (int n = 0; n < 8; ++n) acc[n] = (f32x4_t){0.f, 0.f, 0.f, 0.f};

    for (int chunk = 0; chunk < 4; ++chunk) {
#pragma unroll
        for (int i = 0; i < 4; ++i)
            reinterpret_cast<uint4*>(Bs)[t + (i << 8)] = fBpk[chunk * 1024 + t + (i << 8)];
        __syncthreads();
#pragma unroll
        for (int kk2 = 0; kk2 < 2; ++kk2) {
            const int row = wid * 16 + l15;
            const int abyte = (row << 7) + (kk2 << 6) + (l4 << 4);
            const bf16x8_t af = *reinterpret_cast<const bf16x8_t*>(
                (const char*)Fg[chunk] + (abyte ^ ((row & 7) << 4)));
#pragma unroll
            for (int n = 0; n < 8; ++n) {
                const int o = n * 16 + l15;
                const int bbyte = (o << 7) + (kk2 << 6) + (l4 << 4);
                const bf16x8_t bfr = *reinterpret_cast<const bf16x8_t*>(
                    (const char*)Bs + (bbyte ^ ((o & 7) << 4)));
                acc[n] = __builtin_amdgcn_mfma_f32_16x16x32_bf16(af, bfr, acc[n], 0, 0, 0);
            }
        }
        __syncthreads();
    }

#pragma unroll
    for (int j = 0; j < 4; ++j) {
        const int r = wid * 16 + l4 * 4 + j;
        const int f = f0 + r;
        ushort* gp = gface + ((size_t)b * NFF + f) * 128 + l15;
#pragma unroll
        for (int n = 0; n < 8; ++n)
            gp[n * 16] = f2bf(acc[n][j]);
    }
}

// ---------------------------------------------------------------------------
// mesh_gemm, 64-row blocks, 6 chunks: q0=id (C0), q1=lap (C1), q2=gfc (B=I).
// Grid 1288; b = bid&7 (XCD-pinned), vblk = bid>>3. Stats aliased into Bs.
// ---------------------------------------------------------------------------
__global__ __launch_bounds__(256)
void mesh_gemm_kernel(const ushort* __restrict__ h, const ushort* __restrict__ gface,
                      const uint4* __restrict__ cpk,
                      const float* __restrict__ Lv, const int* __restrict__ Lc,
                      const float* __restrict__ Fv, const int* __restrict__ Fc,
                      ushort* __restrict__ meshraw,
                      float* __restrict__ msum, float* __restrict__ mssq)
{
    __shared__ __align__(16) ushort As[64 * 64];
    __shared__ __align__(16) ushort Bs[128 * 64];
    float* statS = (float*)Bs;
    float* statQ = (float*)Bs + 512;
    __shared__ int   LciS[448];
    __shared__ float LwS[448];
    __shared__ int   FciS[384];
    __shared__ float FwS[384];
    const int t = threadIdx.x;
    const int bid = blockIdx.x;
    const int b = bid & 7;
    const int vblk = bid >> 3;
    const int v0 = vblk * 64;
    const int l = t & 63, wid = t >> 6;
    const int l15 = l & 15, l4 = l >> 4;
    const size_t hb = (size_t)b * NVV * 128;

    for (int i = t; i < 448; i += 256) {
        const int g = v0 * 7 + i;
        if (g < NVV * 7) { LciS[i] = Lc[g]; LwS[i] = Lv[g]; }
    }
    for (int i = t; i < 384; i += 256) {
        const int g = v0 * 6 + i;
        if (g < NVV * 6) { FciS[i] = Fc[g]; FwS[i] = Fv[g]; }
    }
    __syncthreads();

    f32x4_t acc[8];
#pragma unroll
    for (int n = 0; n < 8; ++n) acc[n] = (f32x4_t){0.f, 0.f, 0.f, 0.f};

    for (int chunk = 0; chunk < 6; ++chunk) {
        const int q = chunk >> 1, c0 = (chunk & 1) << 6;
#pragma unroll
        for (int i = 0; i < 2; ++i) {
            const int item = t + (i << 8);
            const int r = item >> 3, piece = item & 7;
            const int cb = c0 + piece * 8;
            const int v = v0 + r;
            uint4 pk = make_uint4(0u, 0u, 0u, 0u);
            if (v < NVV) {
                if (q == 0) {
                    pk = *reinterpret_cast<const uint4*>(h + hb + (size_t)v * 128 + cb);
                } else if (q == 1) {
                    float s[8] = {0.f, 0.f, 0.f, 0.f, 0.f, 0.f, 0.f, 0.f};
#pragma unroll
                    for (int j = 0; j < 7; ++j) {
                        const float w = LwS[r * 7 + j];
                        const int col = LciS[r * 7 + j];
                        const uint4 hv = *reinterpret_cast<const uint4*>(h + hb + (size_t)col * 128 + cb);
                        fma8(hv, w, s);
                    }
                    pk = pack8(s);
                } else {
                    float s[8] = {0.f, 0.f, 0.f, 0.f, 0.f, 0.f, 0.f, 0.f};
#pragma unroll
                    for (int j = 0; j < 6; ++j) {
                        const float w = FwS[r * 6 + j];
                        const int f = FciS[r * 6 + j];
                        const uint4 gv = *reinterpret_cast<const uint4*>(
                            gface + ((size_t)b * NFF + f) * 128 + cb);
                        fma8(gv, w, s);
                    }
                    pk = pack8(s);
                }
            }
            const int byte = (r << 7) + (piece << 4);
            *reinterpret_cast<uint4*>((char*)As + (byte ^ ((r & 7) << 4))) = pk;
        }
#pragma unroll
        for (int i = 0; i < 4; ++i) {
            const int idx = t + (i << 8);
            reinterpret_cast<uint4*>(Bs)[idx] = cpk[chunk * 1024 + idx];
        }
        __syncthreads();
#pragma unroll
        for (int kk2 = 0; kk2 < 2; ++kk2) {
            const int row = wid * 16 + l15;
            const int abyte = (row << 7) + (kk2 << 6) + (l4 << 4);
            const bf16x8_t af = *reinterpret_cast<const bf16x8_t*>(
                (const char*)As + (abyte ^ ((row & 7) << 4)));
#pragma unroll
            for (int n = 0; n < 8; ++n) {
                const int o = n * 16 + l15;
                const int bbyte = (o << 7) + (kk2 << 6) + (l4 << 4);
                const bf16x8_t bfr = *reinterpret_cast<const bf16x8_t*>(
                    (const char*)Bs + (bbyte ^ ((o & 7) << 4)));
                acc[n] = __builtin_amdgcn_mfma_f32_16x16x32_bf16(af, bfr, acc[n], 0, 0, 0);
            }
        }
        __syncthreads();
    }
    // ---- epilogue: meshraw bf16 + per-channel stats ----
    float ss[8], sq[8];
#pragma unroll
    for (int n = 0; n < 8; ++n) { ss[n] = 0.f; sq[n] = 0.f; }
#pragma unroll
    for (int j = 0; j < 4; ++j) {
        const int row = wid * 16 + l4 * 4 + j;
        const int v = v0 + row;
        if (v < NVV) {
            ushort* mp = meshraw + hb + (size_t)v * 128 + l15;
#pragma unroll
            for (int n = 0; n < 8; ++n) {
                const float val = acc[n][j];
                mp[n * 16] = f2bf(val);
                ss[n] += val;
                sq[n] = fmaf(val, val, sq[n]);
            }
        }
    }
#pragma unroll
    for (int n = 0; n < 8; ++n) {
        ss[n] += __shfl_xor(ss[n], 16); ss[n] += __shfl_xor(ss[n], 32);
        sq[n] += __shfl_xor(sq[n], 16); sq[n] += __shfl_xor(sq[n], 32);
    }
    __syncthreads();   // Bs (aliased by stats) dead after last MFMA
    if (l < 16) {
#pragma unroll
        for (int n = 0; n < 8; ++n) {
            statS[wid * 128 + n * 16 + l] = ss[n];
            statQ[wid * 128 + n * 16 + l] = sq[n];
        }
    }
    __syncthreads();
    if (t < 128) {
        const int blk = b * 161 + vblk;
        msum[(size_t)blk * 128 + t] = statS[t] + statS[128 + t] + statS[256 + t] + statS[384 + t];
        mssq[(size_t)blk * 128 + t] = statQ[t] + statQ[128 + t] + statQ[256 + t] + statQ[384 + t];
    }
}

// ---------------------------------------------------------------------------
__global__ __launch_bounds__(256)
void finalize_stats_kernel(const float* __restrict__ s, const float* __restrict__ q, int count,
                           const float* __restrict__ g, const float* __restrict__ be,
                           float* __restrict__ alpha, float* __restrict__ beta, int split)
{
    const int c = blockIdx.x, t = threadIdx.x;
    const size_t base = split ? ((size_t)(c >> 7) * count * 128 + (c & 127)) : (size_t)c;
    float ls = 0.f, lq = 0.f;
    for (int i = t; i < count; i += 256) {
        ls += s[base + (size_t)i * 128];
        lq += q[base + (size_t)i * 128];
    }
    __shared__ float rs[256], rq[256];
    rs[t] = ls; rq[t] = lq;
    __syncthreads();
    for (int off = 128; off > 0; off >>= 1) {
        if (t < off) { rs[t] += rs[t + off]; rq[t] += rq[t + off]; }
        __syncthreads();
    }
    if (t == 0) {
        const float invN = 1.f / (float)(BB * NVV);
        const float mean = rs[0] * invN;
        const float var = rq[0] * invN - mean * mean;
        const float a = g[c] * rsqrtf(var + EPSBN);
        alpha[c] = a;
        beta[c] = be[c] - a * mean;
    }
}

// ---------------------------------------------------------------------------
// K8: out = relu(alpha3*x1 + beta3 + x2)   (x1, x2 bf16 -> out fp32)
// ---------------------------------------------------------------------------
__global__ __launch_bounds__(256)
void final_kernel(float* __restrict__ out, const ushort* __restrict__ x1,
                  const ushort* __restrict__ x2,
                  const float* __restrict__ alpha3, const float* __restrict__ beta3)
{
    const int blk = blockIdx.x;
    const int o = blk & 255;
    const float a = alpha3[o], bb = beta3[o];
    float2* po = reinterpret_cast<float2*>(out + (size_t)blk * NVV);
    const uint* p1 = reinterpret_cast<const uint*>(x1 + (size_t)blk * NVV);
    const uint* p2 = reinterpret_cast<const uint*>(x2 + (size_t)blk * NVV);
    for (int i = threadIdx.x; i < NVV / 2; i += 256) {
        float a1, b1, a2, b2;
        unpack2(p1[i], a1, b1);
        unpack2(p2[i], a2, b2);
        po[i] = make_float2(fmaxf(fmaf(a, a1, bb) + a2, 0.f),
                            fmaxf(fmaf(a, b1, bb) + b2, 0.f));
    }
}

// ---------------------------------------------------------------------------
extern "C" void kernel_launch(void* const* d_in, const int* in_sizes, int n_in,
                              void* d_out, int out_size, void* d_ws, size_t ws_size,
                              hipStream_t stream)
{
    (void)in_sizes; (void)n_in; (void)out_size;
    const float* x      = (const float*)d_in[0];
    const float* w1a    = (const float*)d_in[1];
    const float* g1a    = (const float*)d_in[3];
    const float* be1a   = (const float*)d_in[4];
    const float* coeffs = (const float*)d_in[5];
    const float* g2a    = (const float*)d_in[6];
    const float* be2a   = (const float*)d_in[7];
    const float* w3a    = (const float*)d_in[8];
    const float* g3a    = (const float*)d_in[10];
    const float* be3a   = (const float*)d_in[11];
    const float* w1b    = (const float*)d_in[12];
    const float* g1b    = (const float*)d_in[14];
    const float* be1b   = (const float*)d_in[15];
    const float* Gv     = (const float*)d_in[16];
    const float* Lv     = (const float*)d_in[17];
    const float* Fv     = (const float*)d_in[18];
    const float* EW     = (const float*)d_in[19];
    const float* NSm    = (const float*)d_in[20];
    const int*   Gc     = (const int*)d_in[22];
    const int*   Lc     = (const int*)d_in[24];
    const int*   Fc     = (const int*)d_in[26];

    char* base = (char*)d_ws;
    size_t off = 0;
    auto alloc = [&](size_t bytes) { char* p = base + off; off += (bytes + 255) & ~(size_t)255; return p; };

    // region0 timeline: gramPart+xsumPart -> gface (face/mesh) -> x1 (conv3/final)
    const size_t r0Bytes = (size_t)GRAM_BLOCKS * 16384 * 4 + (size_t)GRAM_BLOCKS * 128 * 4 + 4096;
    char* region0   = alloc(r0Bytes);
    float* gramPart = (float*)region0;
    float* xsumPart = (float*)(region0 + (size_t)GRAM_BLOCKS * 16384 * 4);
    ushort* gface   = (ushort*)region0;                           // 41.9 MB
    ushort* x1      = (ushort*)region0;                           // after gface dead

    ushort* xT      = (ushort*)alloc((size_t)BB * NVV * 128 * 2);
    ushort* h       = (ushort*)alloc((size_t)BB * NVV * 128 * 2);
    ushort* meshraw = (ushort*)alloc((size_t)BB * NVV * 128 * 2);
    ushort* x2      = (ushort*)alloc((size_t)BB * 256 * NVV * 2);
    uint*  cpk      = (uint*)alloc(40960 * 4);
    uint*  wpk      = (uint*)alloc(40960 * 4);
    int*   colp     = (int*)alloc((size_t)NFF * 9 * 4);
    float2* wp      = (float2*)alloc((size_t)NFF * 9 * 8);
    float* Gram     = (float*)alloc(16384 * 4);
    float* xsum     = (float*)alloc(128 * 4);
    float* alpha_a  = (float*)alloc(128 * 4);
    float* beta_a   = (float*)alloc(128 * 4);
    float* alpha_b  = (float*)alloc(256 * 4);
    float* beta_b   = (float*)alloc(256 * 4);
    float* alpha2   = (float*)alloc(128 * 4);
    float* beta2    = (float*)alloc(128 * 4);
    float* alpha3   = (float*)alloc(256 * 4);
    float* beta3    = (float*)alloc(256 * 4);
    float* msum     = (float*)alloc((size_t)1288 * 128 * 4);
    float* mssq     = (float*)alloc((size_t)1288 * 128 * 4);
    float* x1sum    = (float*)alloc((size_t)2 * 1288 * 128 * 4);
    float* x1ssq    = (float*)alloc((size_t)2 * 1288 * 128 * 4);
    if (off > ws_size) return;   // fail loud (validation will catch)

    gram_kernel<<<GRAM_BLOCKS, 256, 0, stream>>>(x, gramPart, xsumPart, (uint*)xT);
    reduce_gram_kernel<<<64, 256, 0, stream>>>(gramPart, xsumPart, Gram, xsum);
    stats_ab_kernel<<<384, 128, 0, stream>>>(Gram, xsum, w1a, g1a, be1a, w1b, g1b, be1b,
                                             alpha_a, beta_a, alpha_b, beta_b);
    prepack_coeffs_kernel<<<160, 256, 0, stream>>>(coeffs, cpk);
    prepack_weights_kernel<<<160, 256, 0, stream>>>(w1a, w1b, w3a, wpk);
    build_meta_kernel<<<(NFF * 9 + 255) / 256, 256, 0, stream>>>(Gv, Gc, EW, NSm, colp, wp);
    mfma_conv_kernel<0><<<1288, 256, 0, stream>>>(
        xT, (const uint4*)wpk, nullptr, nullptr, alpha_a, beta_a, alpha_b, beta_b,
        h, x2, nullptr, nullptr, nullptr);
    face_gemm_kernel<<<(NFF / 64) * 8, 256, 0, stream>>>(
        h, (const uint4*)cpk + 6 * 1024, colp, wp, gface);
    mesh_gemm_kernel<<<1288, 256, 0, stream>>>(h, gface, (const uint4*)cpk,
                                               Lv, Lc, Fv, Fc, meshraw, msum, mssq);
    finalize_stats_kernel<<<128, 256, 0, stream>>>(msum, mssq, 1288, g2a, be2a, alpha2, beta2, 0);
    mfma_conv_kernel<1><<<1288, 256, 0, stream>>>(
        meshraw, (const uint4*)wpk, alpha2, beta2, nullptr, nullptr, nullptr, nullptr,
        nullptr, nullptr, x1, x1sum, x1ssq);
    finalize_stats_kernel<<<256, 256, 0, stream>>>(x1sum, x1ssq, 1288, g3a, be3a, alpha3, beta3, 1);
    final_kernel<<<2048, 256, 0, stream>>>((float*)d_out, x1, x2, alpha3, beta3);
}